// Round 10
// baseline (674.319 us; speedup 1.0000x reference)
//
#include <hip/hip_runtime.h>

#define NN 50000
#define NP 50048
#define NE 800000
#define CH 512
#define NB 196        // ceil(50000/256) scan blocks
#define PB_TRANS 2048 // 2 * CH*CH/256
#define PB_DEG 782    // ceil(NE/4/256)
#define PB_PERM 6     // 3*512/256 permuted-vector blocks
#define SMB 49        // softmax partial blocks (49*1024 >= 50000)

typedef __bf16 bf16x8 __attribute__((ext_vector_type(8)));
typedef float f32x4 __attribute__((ext_vector_type(4)));
typedef unsigned short u16x8 __attribute__((ext_vector_type(8)));

static __device__ __forceinline__ unsigned short f2b(float f){
  unsigned u = __builtin_bit_cast(unsigned, f);
  u = (u + 0x7fffu + ((u >> 16) & 1u)) >> 16;   // RNE f32 -> bf16
  return (unsigned short)u;
}
static __device__ __forceinline__ float b2f(unsigned short h){
  unsigned u = ((unsigned)h) << 16;
  return __builtin_bit_cast(float, u);
}
static __device__ __forceinline__ float rdlane_f(float v, int l){
  return __builtin_bit_cast(float, __builtin_amdgcn_readlane(__builtin_bit_cast(int, v), l));
}
// pack two f32 -> two bf16 (round-half-up) in one dword: 2 adds + 1 v_perm
static __device__ __forceinline__ unsigned pack2(float f0, float f1){
  unsigned u0 = __builtin_bit_cast(unsigned, f0) + 0x8000u;
  unsigned u1 = __builtin_bit_cast(unsigned, f1) + 0x8000u;
  return __builtin_amdgcn_perm(u1, u0, 0x07060302u);  // [u1.hi16 | u0.hi16]
}
// physical column p -> logical channel (epilogue permutation, within 128-blocks)
static __device__ __forceinline__ int lam(int p){
  return (p & ~127) | (((p & 7) << 4) + ((p & 127) >> 3));
}

// ---- prep: W1t | W2t (k-permuted) | deg hist (+edge rank) | permuted vecs ----
__global__ void k_prep(const float* __restrict__ W1, const float* __restrict__ W2,
                       unsigned short* __restrict__ W1t, unsigned short* __restrict__ W2t,
                       const int* __restrict__ ei, int* __restrict__ deg,
                       int* __restrict__ rank,
                       const float* __restrict__ b1, const float* __restrict__ b2,
                       const float* __restrict__ Wo, float* __restrict__ b1p,
                       float* __restrict__ b2p, float* __restrict__ Wop){
  const int b = blockIdx.x, t = threadIdx.x;
  if (b < PB_TRANS){
    int idx = (b & 1023) * 256 + t;
    int n = idx >> 9, p = idx & (CH - 1);
    if (b < 1024)
      W1t[n * CH + p] = f2b(W1[p * CH + n]);            // logical k
    else
      W2t[n * CH + p] = f2b(W2[lam(p) * CH + n]);       // k permuted to match B0 layout
  } else if (b < PB_TRANS + PB_DEG){
    int e4 = ((b - PB_TRANS) * 256 + t) * 4;
    if (e4 < NE){
      int4 d = *(const int4*)(ei + NE + e4);
      int4 r;
      r.x = atomicAdd(&deg[d.x], 1);
      r.y = atomicAdd(&deg[d.y], 1);
      r.z = atomicAdd(&deg[d.z], 1);
      r.w = atomicAdd(&deg[d.w], 1);
      *(int4*)(rank + e4) = r;   // within-node rank; makes bucket atomic-free
    }
  } else {
    int idx = (b - PB_TRANS - PB_DEG) * 256 + t;  // [0,1536)
    int which = idx >> 9, p = idx & (CH - 1);
    int l = lam(p);
    if (which == 0) b1p[p] = b1[l];
    else if (which == 1) b2p[p] = b2[l];
    else Wop[p] = Wo[l];
  }
}

// ---- hierarchical scan: block sums -> scan -> scatter ----
__global__ void k_blocksum(const int* __restrict__ deg, int* __restrict__ bsum){
  __shared__ int sh[4];
  const int t = threadIdx.x;
  int i = blockIdx.x * 256 + t;
  int v = (i < NN) ? deg[i] : 0;
  #pragma unroll
  for (int off = 32; off > 0; off >>= 1) v += __shfl_down(v, off, 64);
  if ((t & 63) == 0) sh[t >> 6] = v;
  __syncthreads();
  if (t == 0) bsum[blockIdx.x] = sh[0] + sh[1] + sh[2] + sh[3];
}

__global__ void k_scanoff(const int* __restrict__ bsum, int* __restrict__ boff,
                          int* __restrict__ row_ptr){
  __shared__ int sh[256];
  const int t = threadIdx.x;
  int v = (t < NB) ? bsum[t] : 0;
  sh[t] = v; __syncthreads();
  for (int d = 1; d < 256; d <<= 1){
    int add = (t >= d) ? sh[t - d] : 0;
    __syncthreads();
    sh[t] += add;
    __syncthreads();
  }
  if (t < NB) boff[t] = sh[t] - v;
  if (t == 255) row_ptr[NN] = sh[255];
}

__global__ void k_scatter(const int* __restrict__ deg, const int* __restrict__ boff,
                          int* __restrict__ row_ptr, float* __restrict__ dinv){
  __shared__ int sh[256];
  const int t = threadIdx.x;
  int i = blockIdx.x * 256 + t;
  int d = (i < NN) ? deg[i] : 0;
  sh[t] = d; __syncthreads();
  for (int dd = 1; dd < 256; dd <<= 1){
    int add = (t >= dd) ? sh[t - dd] : 0;
    __syncthreads();
    sh[t] += add;
    __syncthreads();
  }
  if (i < NN){
    row_ptr[i] = sh[t] - d + boff[blockIdx.x];
    dinv[i] = rsqrtf((float)d + 1.0f);   // +1 self-loop
  }
}

// ---- bucket edges by dst: atomic-free (rank precomputed in k_prep) ----
__global__ void k_bucket(const int* __restrict__ ei, const int* __restrict__ row_ptr,
                         const int* __restrict__ rank, int* __restrict__ csr_src){
  int e2 = (blockIdx.x * blockDim.x + threadIdx.x) * 2;
  if (e2 >= NE) return;
  int2 src = *(const int2*)(ei + e2);
  int2 dst = *(const int2*)(ei + NE + e2);
  int2 rk  = *(const int2*)(rank + e2);
  csr_src[row_ptr[dst.x] + rk.x] = src.x;
  csr_src[row_ptr[dst.y] + rk.y] = src.y;
}

// ---- no-LDS bf16 MFMA GEMM: C[M,512] = A @ Bt^T, 128x256 block tile ----
// Fragments loaded DIRECTLY global->VGPR (16B/lane): A rows L1-resident
// (128 x 128B lines = 16KB), B = W^T 0.5MB L2-resident. Zero LDS, zero
// barriers -> no vmcnt(0) drain; fine-grained per-frag waits keep loads
// in flight (AITER-style). CVT: A is f32 x, converted in-register.
// Permuted epilogue: p = base + l15*8 + j -> one 16B store per (i,r).
template<bool CVT>
__launch_bounds__(256, 2)
__global__ void k_gemm(const void* __restrict__ Av,
                       const unsigned short* __restrict__ Bt,
                       unsigned short* __restrict__ C){
  const int t = threadIdx.x;
  const int wave = t >> 6, lane = t & 63;
  const int quad = lane >> 4, l15 = lane & 15;
  const int mw = (wave & 1) * 64;
  const int nw = (wave >> 1) * 128;
  const int rowBase = (blockIdx.x >> 1) * 128;
  const int nBase = (blockIdx.x & 1) * 256;

  const float* X = (const float*)Av;
  const unsigned short* Ab = (const unsigned short*)Av;
  unsigned aoffs[4];
  #pragma unroll
  for (int i=0;i<4;i++){
    int r = rowBase + mw + i*16 + l15;
    if (CVT && r >= NN) r = 0;      // clamp: C pad rows never consumed
    aoffs[i] = (unsigned)r * CH + quad*8;
  }
  unsigned boffs[8];
  #pragma unroll
  for (int j=0;j<8;j++)
    boffs[j] = (unsigned)(nBase + nw + j*16 + l15) * CH + quad*8;

  f32x4 acc[4][8];
  #pragma unroll
  for (int i=0;i<4;i++)
    #pragma unroll
    for (int j=0;j<8;j++) acc[i][j] = 0;

  for (int kb = 0; kb < CH; kb += 32){
    bf16x8 af[4], bfr[8];
    if (CVT){
      float4 a0[4], a1[4];
      #pragma unroll
      for (int i=0;i<4;i++){
        a0[i] = *(const float4*)(X + aoffs[i] + kb);
        a1[i] = *(const float4*)(X + aoffs[i] + kb + 4);
      }
      #pragma unroll
      for (int i=0;i<4;i++){
        uint4 pk;
        pk.x = pack2(a0[i].x, a0[i].y); pk.y = pack2(a0[i].z, a0[i].w);
        pk.z = pack2(a1[i].x, a1[i].y); pk.w = pack2(a1[i].z, a1[i].w);
        af[i] = __builtin_bit_cast(bf16x8, pk);
      }
    } else {
      #pragma unroll
      for (int i=0;i<4;i++)
        af[i] = __builtin_bit_cast(bf16x8, *(const u16x8*)(Ab + aoffs[i] + kb));
    }
    #pragma unroll
    for (int j=0;j<8;j++)
      bfr[j] = __builtin_bit_cast(bf16x8, *(const u16x8*)(Bt + boffs[j] + kb));
    #pragma unroll
    for (int i=0;i<4;i++)
      #pragma unroll
      for (int j=0;j<8;j++)
        acc[i][j] = __builtin_amdgcn_mfma_f32_16x16x32_bf16(af[i], bfr[j], acc[i][j], 0, 0, 0);
  }

  // permuted epilogue: lane packs its 8 j-values of one row -> 16B store
  #pragma unroll
  for (int i=0;i<4;i++){
    #pragma unroll
    for (int r=0;r<4;r++){
      int row = rowBase + mw + i*16 + quad*4 + r;
      u16x8 o;
      #pragma unroll
      for (int j=0;j<8;j++) o[j] = f2b(acc[i][j][r]);
      *(u16x8*)(C + (size_t)row * CH + nBase + nw + l15*8) = o;
    }
  }
}

// ---- aggregation: relu(di*sum + di^2*self + b); optional fused head ----
template<bool HEAD>
__launch_bounds__(256)
__global__ void k_agg(const unsigned short* __restrict__ h, const int* __restrict__ row_ptr,
                      const int* __restrict__ csr_src, const float* __restrict__ dinv,
                      const float* __restrict__ bias, unsigned short* __restrict__ out,
                      const float* __restrict__ Wo, const float* __restrict__ bo,
                      float* __restrict__ logits){
  const int node = blockIdx.x * 4 + (threadIdx.x >> 6);
  const int lane = threadIdx.x & 63;
  float acc[8];
  #pragma unroll
  for (int k=0;k<8;k++) acc[k] = 0.f;
  const int rp = row_ptr[node], re = row_ptr[node + 1];
  for (int base = rp; base < re; base += 64){
    int cnt = re - base; if (cnt > 64) cnt = 64;
    int s = 0; float w = 0.f;
    if (base + lane < re){ s = csr_src[base + lane]; w = dinv[s]; }
    int j = 0;
    for (; j + 8 <= cnt; j += 8){
      int ss[8]; float ww[8]; u16x8 hv[8];
      #pragma unroll
      for (int u=0;u<8;u++){
        ss[u] = __builtin_amdgcn_readlane(s, j + u);
        ww[u] = rdlane_f(w, j + u);
      }
      #pragma unroll
      for (int u=0;u<8;u++)
        hv[u] = *(const u16x8*)(h + (size_t)ss[u] * CH + lane * 8);
      #pragma unroll
      for (int u=0;u<8;u++)
        #pragma unroll
        for (int k=0;k<8;k++) acc[k] += ww[u] * b2f(hv[u][k]);
    }
    for (; j < cnt; j++){
      int ss = __builtin_amdgcn_readlane(s, j);
      float ww = rdlane_f(w, j);
      u16x8 hv = *(const u16x8*)(h + (size_t)ss * CH + lane * 8);
      #pragma unroll
      for (int k=0;k<8;k++) acc[k] += ww * b2f(hv[k]);
    }
  }
  const float di = dinv[node];
  u16x8 hs = *(const u16x8*)(h + (size_t)node * CH + lane * 8);
  const float4* bp = (const float4*)(bias + lane * 8);
  float4 bv0 = bp[0], bv1 = bp[1];
  float bb[8] = {bv0.x,bv0.y,bv0.z,bv0.w,bv1.x,bv1.y,bv1.z,bv1.w};
  if (HEAD){
    const float4* wp = (const float4*)(Wo + lane * 8);
    float4 w0 = wp[0], w1 = wp[1];
    float wv[8] = {w0.x,w0.y,w0.z,w0.w,w1.x,w1.y,w1.z,w1.w};
    float v = 0.f;
    #pragma unroll
    for (int k=0;k<8;k++){
      float r = fmaxf(di * acc[k] + di * di * b2f(hs[k]) + bb[k], 0.f);
      v += r * wv[k];
    }
    #pragma unroll
    for (int off = 32; off > 0; off >>= 1) v += __shfl_down(v, off, 64);
    if (lane == 0) logits[node] = v + bo[0];
  } else {
    u16x8 o;
    #pragma unroll
    for (int k=0;k<8;k++){
      float r = fmaxf(di * acc[k] + di * di * b2f(hs[k]) + bb[k], 0.f);
      o[k] = f2b(r);
    }
    *(u16x8*)(out + (size_t)node * CH + lane * 8) = o;
  }
}

// ---- softmax: 49-block partial (m_b, s_b); final combine folded into write ----
__global__ void k_smpart(const float* __restrict__ logits, float* __restrict__ pm,
                         float* __restrict__ ps){
  __shared__ float shm[16], shs[16];
  const int t = threadIdx.x;
  const int i = blockIdx.x * 1024 + t;
  float v = (i < NN) ? logits[i] : -3.4e38f;
  float m = v;
  #pragma unroll
  for (int off = 32; off > 0; off >>= 1) m = fmaxf(m, __shfl_down(m, off, 64));
  if ((t & 63) == 0) shm[t >> 6] = m;
  __syncthreads();
  if (t < 64){
    float mm = (t < 16) ? shm[t] : -3.4e38f;
    #pragma unroll
    for (int off = 8; off > 0; off >>= 1) mm = fmaxf(mm, __shfl_down(mm, off, 64));
    if (t == 0) shm[0] = mm;
  }
  __syncthreads();
  const float bm = shm[0];
  float s = (i < NN) ? expf(v - bm) : 0.f;
  #pragma unroll
  for (int off = 32; off > 0; off >>= 1) s += __shfl_down(s, off, 64);
  if ((t & 63) == 0) shs[t >> 6] = s;
  __syncthreads();
  if (t < 64){
    float sss = (t < 16) ? shs[t] : 0.f;
    #pragma unroll
    for (int off = 8; off > 0; off >>= 1) sss += __shfl_down(sss, off, 64);
    if (t == 0){ pm[blockIdx.x] = bm; ps[blockIdx.x] = sss; }
  }
}

__global__ void k_smwrite(const float* __restrict__ logits, const float* __restrict__ pm,
                          const float* __restrict__ ps, float* __restrict__ out){
  __shared__ float shMS[2];
  const int t = threadIdx.x;
  if (t < 64){
    float m = (t < SMB) ? pm[t] : -3.4e38f;
    float M = m;
    #pragma unroll
    for (int off = 32; off > 0; off >>= 1) M = fmaxf(M, __shfl_down(M, off, 64));
    M = rdlane_f(M, 0);
    float s = (t < SMB) ? ps[t] * expf(m - M) : 0.f;
    #pragma unroll
    for (int off = 32; off > 0; off >>= 1) s += __shfl_down(s, off, 64);
    if (t == 0){ shMS[0] = M; shMS[1] = s; }
  }
  __syncthreads();
  int i = blockIdx.x * blockDim.x + t;
  if (i < NN) out[i] = expf(logits[i] - shMS[0]) / shMS[1];
}

extern "C" void kernel_launch(void* const* d_in, const int* in_sizes, int n_in,
                              void* d_out, int out_size, void* d_ws, size_t ws_size,
                              hipStream_t stream){
  const float* x  = (const float*)d_in[0];
  const int*   ei = (const int*)d_in[1];
  const float* W1 = (const float*)d_in[2];
  const float* b1 = (const float*)d_in[3];
  const float* W2 = (const float*)d_in[4];
  const float* b2 = (const float*)d_in[5];
  const float* Wo = (const float*)d_in[6];
  const float* bo = (const float*)d_in[7];
  float* out = (float*)d_out;

  char* ws = (char*)d_ws;
  size_t off = 0;
  auto alloc = [&](size_t bytes) -> void* {
    void* p = ws + off;
    off = (off + bytes + 255) & ~(size_t)255;
    return p;
  };
  unsigned short* B0  = (unsigned short*)alloc((size_t)NP * CH * 2);
  unsigned short* B1  = (unsigned short*)alloc((size_t)NP * CH * 2);
  unsigned short* W1t = (unsigned short*)alloc((size_t)CH * CH * 2);
  unsigned short* W2t = (unsigned short*)alloc((size_t)CH * CH * 2);
  int*   deg     = (int*)alloc((size_t)NN * 4);
  float* dinv    = (float*)alloc((size_t)NN * 4);
  int*   row_ptr = (int*)alloc((size_t)(NN + 1) * 4);
  int*   rank    = (int*)alloc((size_t)NE * 4);
  int*   csr     = (int*)alloc((size_t)NE * 4);
  float* logits  = (float*)alloc((size_t)NN * 4);
  int*   bsum    = (int*)alloc((size_t)NB * 4);
  int*   boff    = (int*)alloc((size_t)NB * 4);
  float* pm      = (float*)alloc((size_t)SMB * 4);
  float* ps      = (float*)alloc((size_t)SMB * 4);
  float* b1p     = (float*)alloc((size_t)CH * 4);
  float* b2p     = (float*)alloc((size_t)CH * 4);
  float* Wop     = (float*)alloc((size_t)CH * 4);

  hipMemsetAsync(deg, 0, (size_t)NN * 4, stream);
  k_prep<<<PB_TRANS + PB_DEG + PB_PERM, 256, 0, stream>>>(
      W1, W2, W1t, W2t, ei, deg, rank, b1, b2, Wo, b1p, b2p, Wop);
  k_blocksum<<<NB, 256, 0, stream>>>(deg, bsum);
  k_scanoff<<<1, 256, 0, stream>>>(bsum, boff, row_ptr);
  k_scatter<<<NB, 256, 0, stream>>>(deg, boff, row_ptr, dinv);
  k_bucket<<<(NE / 2 + 255) / 256, 256, 0, stream>>>(ei, row_ptr, rank, csr);

  k_gemm<true><<<2 * (NP / 128), 256, 0, stream>>>(x, W1t, B1);    // fused f32->bf16, no LDS
  k_agg<false><<<NN / 4, 256, 0, stream>>>(B1, row_ptr, csr, dinv, b1p, B0,
                                           Wop, bo, logits);
  k_gemm<false><<<2 * (NP / 128), 256, 0, stream>>>(B0, W2t, B1);  // no LDS
  k_agg<true><<<NN / 4, 256, 0, stream>>>(B1, row_ptr, csr, dinv, b2p, B0,
                                          Wop, bo, logits);

  k_smpart<<<SMB, 1024, 0, stream>>>(logits, pm, ps);
  k_smwrite<<<NB, 256, 0, stream>>>(logits, pm, ps, out);
}

// Round 11
// 547.978 us; speedup vs baseline: 1.2306x; 1.2306x over previous
//
#include <hip/hip_runtime.h>

#define NN 50000
#define NP 50048
#define NE 800000
#define CH 512
#define NB 196        // ceil(50000/256) scan blocks
#define PB_TRANS 2048 // 2 * CH*CH/256
#define PB_DEG 782    // ceil(NE/4/256)
#define PB_PERM 6     // 3*512/256 permuted-vector blocks
#define SMB 49        // softmax partial blocks (49*1024 >= 50000)
#define GB1 (2 * (NP / 128))          // 782 gemm blocks
#define BKB ((NE / 2 + 255) / 256)    // 1563 bucket blocks

typedef __bf16 bf16x8 __attribute__((ext_vector_type(8)));
typedef float f32x4 __attribute__((ext_vector_type(4)));
typedef unsigned short u16x8 __attribute__((ext_vector_type(8)));

static __device__ __forceinline__ unsigned short f2b(float f){
  unsigned u = __builtin_bit_cast(unsigned, f);
  u = (u + 0x7fffu + ((u >> 16) & 1u)) >> 16;   // RNE f32 -> bf16
  return (unsigned short)u;
}
static __device__ __forceinline__ float b2f(unsigned short h){
  unsigned u = ((unsigned)h) << 16;
  return __builtin_bit_cast(float, u);
}
static __device__ __forceinline__ float rdlane_f(float v, int l){
  return __builtin_bit_cast(float, __builtin_amdgcn_readlane(__builtin_bit_cast(int, v), l));
}
// pack two f32 -> two bf16 (round-half-up) in one dword: 2 adds + 1 v_perm
static __device__ __forceinline__ unsigned pack2(float f0, float f1){
  unsigned u0 = __builtin_bit_cast(unsigned, f0) + 0x8000u;
  unsigned u1 = __builtin_bit_cast(unsigned, f1) + 0x8000u;
  return __builtin_amdgcn_perm(u1, u0, 0x07060302u);  // [u1.hi16 | u0.hi16]
}
// physical column p -> logical channel (epilogue permutation, within 128-blocks)
static __device__ __forceinline__ int lam(int p){
  return (p & ~127) | (((p & 7) << 4) + ((p & 127) >> 3));
}

// ---- prep: W1t | W2t (k-permuted) | deg hist (+edge rank) | permuted vecs ----
__global__ void k_prep(const float* __restrict__ W1, const float* __restrict__ W2,
                       unsigned short* __restrict__ W1t, unsigned short* __restrict__ W2t,
                       const int* __restrict__ ei, int* __restrict__ deg,
                       int* __restrict__ rank,
                       const float* __restrict__ b1, const float* __restrict__ b2,
                       const float* __restrict__ Wo, float* __restrict__ b1p,
                       float* __restrict__ b2p, float* __restrict__ Wop){
  const int b = blockIdx.x, t = threadIdx.x;
  if (b < PB_TRANS){
    int idx = (b & 1023) * 256 + t;
    int n = idx >> 9, p = idx & (CH - 1);
    if (b < 1024)
      W1t[n * CH + p] = f2b(W1[p * CH + n]);            // logical k
    else
      W2t[n * CH + p] = f2b(W2[lam(p) * CH + n]);       // k permuted to match B0 layout
  } else if (b < PB_TRANS + PB_DEG){
    int e4 = ((b - PB_TRANS) * 256 + t) * 4;
    if (e4 < NE){
      int4 d = *(const int4*)(ei + NE + e4);
      int4 r;
      r.x = atomicAdd(&deg[d.x], 1);
      r.y = atomicAdd(&deg[d.y], 1);
      r.z = atomicAdd(&deg[d.z], 1);
      r.w = atomicAdd(&deg[d.w], 1);
      *(int4*)(rank + e4) = r;   // within-node rank; makes bucket atomic-free
    }
  } else {
    int idx = (b - PB_TRANS - PB_DEG) * 256 + t;  // [0,1536)
    int which = idx >> 9, p = idx & (CH - 1);
    int l = lam(p);
    if (which == 0) b1p[p] = b1[l];
    else if (which == 1) b2p[p] = b2[l];
    else Wop[p] = Wo[l];
  }
}

// ---- hierarchical scan: block sums -> scan -> scatter ----
__global__ void k_blocksum(const int* __restrict__ deg, int* __restrict__ bsum){
  __shared__ int sh[4];
  const int t = threadIdx.x;
  int i = blockIdx.x * 256 + t;
  int v = (i < NN) ? deg[i] : 0;
  #pragma unroll
  for (int off = 32; off > 0; off >>= 1) v += __shfl_down(v, off, 64);
  if ((t & 63) == 0) sh[t >> 6] = v;
  __syncthreads();
  if (t == 0) bsum[blockIdx.x] = sh[0] + sh[1] + sh[2] + sh[3];
}

__global__ void k_scanoff(const int* __restrict__ bsum, int* __restrict__ boff,
                          int* __restrict__ row_ptr){
  __shared__ int sh[256];
  const int t = threadIdx.x;
  int v = (t < NB) ? bsum[t] : 0;
  sh[t] = v; __syncthreads();
  for (int d = 1; d < 256; d <<= 1){
    int add = (t >= d) ? sh[t - d] : 0;
    __syncthreads();
    sh[t] += add;
    __syncthreads();
  }
  if (t < NB) boff[t] = sh[t] - v;
  if (t == 255) row_ptr[NN] = sh[255];
}

__global__ void k_scatter(const int* __restrict__ deg, const int* __restrict__ boff,
                          int* __restrict__ row_ptr, float* __restrict__ dinv){
  __shared__ int sh[256];
  const int t = threadIdx.x;
  int i = blockIdx.x * 256 + t;
  int d = (i < NN) ? deg[i] : 0;
  sh[t] = d; __syncthreads();
  for (int dd = 1; dd < 256; dd <<= 1){
    int add = (t >= dd) ? sh[t - dd] : 0;
    __syncthreads();
    sh[t] += add;
    __syncthreads();
  }
  if (i < NN){
    row_ptr[i] = sh[t] - d + boff[blockIdx.x];
    dinv[i] = rsqrtf((float)d + 1.0f);   // +1 self-loop
  }
}

// ---- LDS-staged dbuf GEMM body (round-8/9 proven structure) ----
// CVT: A is f32 x, loaded to regs, converted in MFMA shadow, ds_write to nxt.
// else: A via async global_load_lds. B always async global_load_lds.
template<bool CVT>
static __device__ __forceinline__ void gemm_body(
    const int bx, const int t,
    const void* __restrict__ Av, const unsigned short* __restrict__ Bt,
    unsigned short* __restrict__ C,
    unsigned short (&As)[2][4096], unsigned short (&Bs)[2][8192]){
  const int wave = t >> 6, lane = t & 63;
  const int quad = lane >> 4, l15 = lane & 15;
  const int mw = (wave & 1) * 64;
  const int nw = (wave >> 1) * 128;
  const int rowBase = (bx >> 1) * 128;
  const int nBase = (bx & 1) * 256;

  const int lr = lane >> 2;              // 16-row async chunks
  const int lc = (lane & 3) * 8;
  const int lr8 = lane >> 3;             // 8-row f32 chunks (CVT path)
  const int lc8 = lane & 7;
  const unsigned short* Bg0 = Bt + (size_t)(nBase + wave * 64 + lr) * CH + lc;
  const int boff = wave * 4 * 512;
  const float* X = (const float*)Av;
  const unsigned short* Ag0 = (const unsigned short*)Av;
  if (!CVT) Ag0 += (size_t)(rowBase + wave * 32 + lr) * CH + lc;
  const int aoff = wave * 2 * 512;

  int arow[4]; size_t asrc[4];
  if (CVT){
    #pragma unroll
    for (int q=0;q<4;q++){
      arow[q] = wave * 32 + q * 8 + lr8;               // local row in tile
      int gr = rowBase + arow[q];
      if (gr >= NN) gr = 0;                            // clamp: pad rows unread
      asrc[q] = (size_t)gr * CH + lc8 * 4;
    }
  }

  f32x4 acc[4][8];
  #pragma unroll
  for (int i=0;i<4;i++)
    #pragma unroll
    for (int j=0;j<8;j++) acc[i][j] = 0;

  // ---- prologue: tile 0 ----
  float4 apre[4];
  if (CVT){
    #pragma unroll
    for (int q=0;q<4;q++) apre[q] = *(const float4*)(X + asrc[q]);
    #pragma unroll
    for (int q=0;q<4;q++){
      uint2 pk; pk.x = pack2(apre[q].x, apre[q].y); pk.y = pack2(apre[q].z, apre[q].w);
      *(uint2*)&As[0][arow[q] * 32 + lc8 * 4] = pk;
    }
  } else {
    #pragma unroll
    for (int q=0;q<2;q++)
      __builtin_amdgcn_global_load_lds(
        (const __attribute__((address_space(1))) void*)(Ag0 + (size_t)q*16*CH),
        (__attribute__((address_space(3))) void*)(&As[0][aoff + q*512]), 16, 0, 0);
  }
  #pragma unroll
  for (int q=0;q<4;q++)
    __builtin_amdgcn_global_load_lds(
      (const __attribute__((address_space(1))) void*)(Bg0 + (size_t)q*16*CH),
      (__attribute__((address_space(3))) void*)(&Bs[0][boff + q*512]), 16, 0, 0);

  for (int it = 0; it < 16; it++){
    const int cur = it & 1, nxt = cur ^ 1;
    __syncthreads();   // tile `cur` fully staged; `nxt` free
    if (it < 15){
      const int kb = (it + 1) * 32;
      if (CVT){
        #pragma unroll
        for (int q=0;q<4;q++) apre[q] = *(const float4*)(X + asrc[q] + kb);
      } else {
        #pragma unroll
        for (int q=0;q<2;q++)
          __builtin_amdgcn_global_load_lds(
            (const __attribute__((address_space(1))) void*)(Ag0 + (size_t)q*16*CH + kb),
            (__attribute__((address_space(3))) void*)(&As[nxt][aoff + q*512]), 16, 0, 0);
      }
      #pragma unroll
      for (int q=0;q<4;q++)
        __builtin_amdgcn_global_load_lds(
          (const __attribute__((address_space(1))) void*)(Bg0 + (size_t)q*16*CH + kb),
          (__attribute__((address_space(3))) void*)(&Bs[nxt][boff + q*512]), 16, 0, 0);
    }
    bf16x8 af[4], bfr[8];
    #pragma unroll
    for (int i=0;i<4;i++)
      af[i] = __builtin_bit_cast(bf16x8,
              *(const u16x8*)&As[cur][(mw + i*16 + l15) * 32 + quad * 8]);
    #pragma unroll
    for (int j=0;j<8;j++)
      bfr[j] = __builtin_bit_cast(bf16x8,
              *(const u16x8*)&Bs[cur][(nw + j*16 + l15) * 32 + quad * 8]);
    #pragma unroll
    for (int i=0;i<4;i++)
      #pragma unroll
      for (int j=0;j<8;j++)
        acc[i][j] = __builtin_amdgcn_mfma_f32_16x16x32_bf16(af[i], bfr[j], acc[i][j], 0, 0, 0);
    if (CVT && it < 15){   // convert in the MFMA shadow, write into nxt
      #pragma unroll
      for (int q=0;q<4;q++){
        uint2 pk; pk.x = pack2(apre[q].x, apre[q].y); pk.y = pack2(apre[q].z, apre[q].w);
        *(uint2*)&As[nxt][arow[q] * 32 + lc8 * 4] = pk;
      }
    }
  }

  // permuted epilogue: lane packs its 8 j-values of one row -> 16B store
  #pragma unroll
  for (int i=0;i<4;i++){
    #pragma unroll
    for (int r=0;r<4;r++){
      int row = rowBase + mw + i*16 + quad*4 + r;
      u16x8 o;
      #pragma unroll
      for (int j=0;j<8;j++) o[j] = f2b(acc[i][j][r]);
      *(u16x8*)(C + (size_t)row * CH + nBase + nw + l15*8) = o;
    }
  }
}

// ---- fused: gemm1 (CVT, f32 x -> bf16 C) || bucket scatter ----
// blocks [0,GB1) run gemm; [GB1, GB1+BKB) run the atomic-free CSR bucket.
// Bucket traffic (~15 MB scatter) fills gemm1's latency bubbles; saves a launch.
__launch_bounds__(256, 2)
__global__ void k_g1bkt(const float* __restrict__ x, const unsigned short* __restrict__ W1t,
                        unsigned short* __restrict__ C,
                        const int* __restrict__ ei, const int* __restrict__ row_ptr,
                        const int* __restrict__ rank, int* __restrict__ csr_src){
  __shared__ __align__(16) unsigned short As[2][4096];
  __shared__ __align__(16) unsigned short Bs[2][8192];
  const int b = blockIdx.x;
  if (b < GB1){
    gemm_body<true>(b, threadIdx.x, x, W1t, C, As, Bs);
  } else {
    int e2 = ((b - GB1) * 256 + threadIdx.x) * 2;
    if (e2 < NE){
      int2 src = *(const int2*)(ei + e2);
      int2 dst = *(const int2*)(ei + NE + e2);
      int2 rk  = *(const int2*)(rank + e2);
      csr_src[row_ptr[dst.x] + rk.x] = src.x;
      csr_src[row_ptr[dst.y] + rk.y] = src.y;
    }
  }
}

// ---- gemm2: bf16 A (B0), LDS dbuf ----
__launch_bounds__(256, 2)
__global__ void k_gemm2(const unsigned short* __restrict__ A,
                        const unsigned short* __restrict__ Bt,
                        unsigned short* __restrict__ C){
  __shared__ __align__(16) unsigned short As[2][4096];
  __shared__ __align__(16) unsigned short Bs[2][8192];
  gemm_body<false>(blockIdx.x, threadIdx.x, A, Bt, C, As, Bs);
}

// ---- aggregation: relu(di*sum + di^2*self + b); optional fused head ----
template<bool HEAD>
__launch_bounds__(256)
__global__ void k_agg(const unsigned short* __restrict__ h, const int* __restrict__ row_ptr,
                      const int* __restrict__ csr_src, const float* __restrict__ dinv,
                      const float* __restrict__ bias, unsigned short* __restrict__ out,
                      const float* __restrict__ Wo, const float* __restrict__ bo,
                      float* __restrict__ logits){
  const int node = blockIdx.x * 4 + (threadIdx.x >> 6);
  const int lane = threadIdx.x & 63;
  float acc[8];
  #pragma unroll
  for (int k=0;k<8;k++) acc[k] = 0.f;
  const int rp = row_ptr[node], re = row_ptr[node + 1];
  for (int base = rp; base < re; base += 64){
    int cnt = re - base; if (cnt > 64) cnt = 64;
    int s = 0; float w = 0.f;
    if (base + lane < re){ s = csr_src[base + lane]; w = dinv[s]; }
    int j = 0;
    for (; j + 8 <= cnt; j += 8){
      int ss[8]; float ww[8]; u16x8 hv[8];
      #pragma unroll
      for (int u=0;u<8;u++){
        ss[u] = __builtin_amdgcn_readlane(s, j + u);
        ww[u] = rdlane_f(w, j + u);
      }
      #pragma unroll
      for (int u=0;u<8;u++)
        hv[u] = *(const u16x8*)(h + (size_t)ss[u] * CH + lane * 8);
      #pragma unroll
      for (int u=0;u<8;u++)
        #pragma unroll
        for (int k=0;k<8;k++) acc[k] += ww[u] * b2f(hv[u][k]);
    }
    for (; j < cnt; j++){
      int ss = __builtin_amdgcn_readlane(s, j);
      float ww = rdlane_f(w, j);
      u16x8 hv = *(const u16x8*)(h + (size_t)ss * CH + lane * 8);
      #pragma unroll
      for (int k=0;k<8;k++) acc[k] += ww * b2f(hv[k]);
    }
  }
  const float di = dinv[node];
  u16x8 hs = *(const u16x8*)(h + (size_t)node * CH + lane * 8);
  const float4* bp = (const float4*)(bias + lane * 8);
  float4 bv0 = bp[0], bv1 = bp[1];
  float bb[8] = {bv0.x,bv0.y,bv0.z,bv0.w,bv1.x,bv1.y,bv1.z,bv1.w};
  if (HEAD){
    const float4* wp = (const float4*)(Wo + lane * 8);
    float4 w0 = wp[0], w1 = wp[1];
    float wv[8] = {w0.x,w0.y,w0.z,w0.w,w1.x,w1.y,w1.z,w1.w};
    float v = 0.f;
    #pragma unroll
    for (int k=0;k<8;k++){
      float r = fmaxf(di * acc[k] + di * di * b2f(hs[k]) + bb[k], 0.f);
      v += r * wv[k];
    }
    #pragma unroll
    for (int off = 32; off > 0; off >>= 1) v += __shfl_down(v, off, 64);
    if (lane == 0) logits[node] = v + bo[0];
  } else {
    u16x8 o;
    #pragma unroll
    for (int k=0;k<8;k++){
      float r = fmaxf(di * acc[k] + di * di * b2f(hs[k]) + bb[k], 0.f);
      o[k] = f2b(r);
    }
    *(u16x8*)(out + (size_t)node * CH + lane * 8) = o;
  }
}

// ---- softmax: 49-block partial (m_b, s_b); final combine folded into write ----
__global__ void k_smpart(const float* __restrict__ logits, float* __restrict__ pm,
                         float* __restrict__ ps){
  __shared__ float shm[16], shs[16];
  const int t = threadIdx.x;
  const int i = blockIdx.x * 1024 + t;
  float v = (i < NN) ? logits[i] : -3.4e38f;
  float m = v;
  #pragma unroll
  for (int off = 32; off > 0; off >>= 1) m = fmaxf(m, __shfl_down(m, off, 64));
  if ((t & 63) == 0) shm[t >> 6] = m;
  __syncthreads();
  if (t < 64){
    float mm = (t < 16) ? shm[t] : -3.4e38f;
    #pragma unroll
    for (int off = 8; off > 0; off >>= 1) mm = fmaxf(mm, __shfl_down(mm, off, 64));
    if (t == 0) shm[0] = mm;
  }
  __syncthreads();
  const float bm = shm[0];
  float s = (i < NN) ? expf(v - bm) : 0.f;
  #pragma unroll
  for (int off = 32; off > 0; off >>= 1) s += __shfl_down(s, off, 64);
  if ((t & 63) == 0) shs[t >> 6] = s;
  __syncthreads();
  if (t < 64){
    float sss = (t < 16) ? shs[t] : 0.f;
    #pragma unroll
    for (int off = 8; off > 0; off >>= 1) sss += __shfl_down(sss, off, 64);
    if (t == 0){ pm[blockIdx.x] = bm; ps[blockIdx.x] = sss; }
  }
}

__global__ void k_smwrite(const float* __restrict__ logits, const float* __restrict__ pm,
                          const float* __restrict__ ps, float* __restrict__ out){
  __shared__ float shMS[2];
  const int t = threadIdx.x;
  if (t < 64){
    float m = (t < SMB) ? pm[t] : -3.4e38f;
    float M = m;
    #pragma unroll
    for (int off = 32; off > 0; off >>= 1) M = fmaxf(M, __shfl_down(M, off, 64));
    M = rdlane_f(M, 0);
    float s = (t < SMB) ? ps[t] * expf(m - M) : 0.f;
    #pragma unroll
    for (int off = 32; off > 0; off >>= 1) s += __shfl_down(s, off, 64);
    if (t == 0){ shMS[0] = M; shMS[1] = s; }
  }
  __syncthreads();
  int i = blockIdx.x * blockDim.x + t;
  if (i < NN) out[i] = expf(logits[i] - shMS[0]) / shMS[1];
}

extern "C" void kernel_launch(void* const* d_in, const int* in_sizes, int n_in,
                              void* d_out, int out_size, void* d_ws, size_t ws_size,
                              hipStream_t stream){
  const float* x  = (const float*)d_in[0];
  const int*   ei = (const int*)d_in[1];
  const float* W1 = (const float*)d_in[2];
  const float* b1 = (const float*)d_in[3];
  const float* W2 = (const float*)d_in[4];
  const float* b2 = (const float*)d_in[5];
  const float* Wo = (const float*)d_in[6];
  const float* bo = (const float*)d_in[7];
  float* out = (float*)d_out;

  char* ws = (char*)d_ws;
  size_t off = 0;
  auto alloc = [&](size_t bytes) -> void* {
    void* p = ws + off;
    off = (off + bytes + 255) & ~(size_t)255;
    return p;
  };
  unsigned short* B0  = (unsigned short*)alloc((size_t)NP * CH * 2);
  unsigned short* B1  = (unsigned short*)alloc((size_t)NP * CH * 2);
  unsigned short* W1t = (unsigned short*)alloc((size_t)CH * CH * 2);
  unsigned short* W2t = (unsigned short*)alloc((size_t)CH * CH * 2);
  int*   deg     = (int*)alloc((size_t)NN * 4);
  float* dinv    = (float*)alloc((size_t)NN * 4);
  int*   row_ptr = (int*)alloc((size_t)(NN + 1) * 4);
  int*   rank    = (int*)alloc((size_t)NE * 4);
  int*   csr     = (int*)alloc((size_t)NE * 4);
  float* logits  = (float*)alloc((size_t)NN * 4);
  int*   bsum    = (int*)alloc((size_t)NB * 4);
  int*   boff    = (int*)alloc((size_t)NB * 4);
  float* pm      = (float*)alloc((size_t)SMB * 4);
  float* ps      = (float*)alloc((size_t)SMB * 4);
  float* b1p     = (float*)alloc((size_t)CH * 4);
  float* b2p     = (float*)alloc((size_t)CH * 4);
  float* Wop     = (float*)alloc((size_t)CH * 4);

  hipMemsetAsync(deg, 0, (size_t)NN * 4, stream);
  k_prep<<<PB_TRANS + PB_DEG + PB_PERM, 256, 0, stream>>>(
      W1, W2, W1t, W2t, ei, deg, rank, b1, b2, Wo, b1p, b2p, Wop);
  k_blocksum<<<NB, 256, 0, stream>>>(deg, bsum);
  k_scanoff<<<1, 256, 0, stream>>>(bsum, boff, row_ptr);
  k_scatter<<<NB, 256, 0, stream>>>(deg, boff, row_ptr, dinv);

  k_g1bkt<<<GB1 + BKB, 256, 0, stream>>>(x, W1t, B1, ei, row_ptr, rank, csr);
  k_agg<false><<<NN / 4, 256, 0, stream>>>(B1, row_ptr, csr, dinv, b1p, B0,
                                           Wop, bo, logits);
  k_gemm2<<<GB1, 256, 0, stream>>>(B0, W2t, B1);
  k_agg<true><<<NN / 4, 256, 0, stream>>>(B1, row_ptr, csr, dinv, b2p, B0,
                                          Wop, bo, logits);

  k_smpart<<<SMB, 1024, 0, stream>>>(logits, pm, ps);
  k_smwrite<<<NB, 256, 0, stream>>>(logits, pm, ps, out);
}